// Round 5
// baseline (1418.341 us; speedup 1.0000x reference)
//
#include <hip/hip_runtime.h>
#include <hip/hip_bf16.h>

#define NIMG 32
#define NPTS 300000
#define NL   64
#define NBOX 256
#define NBAND 8
#define BROWS 32           // NBOX / NBAND
#define QSUB 4
#define NBIN (NIMG * NBAND * QSUB)   // 1024

__device__ __forceinline__ int rev8(int x) { return (int)(__brev((unsigned)x) >> 24); }

// native LDS float atomic add (ds_add_f32, no return).
__device__ __forceinline__ void lds_fadd(float* p, float v) {
    unsigned off = (unsigned)(uintptr_t)p;
    asm volatile("ds_add_f32 %0, %1" :: "v"(off), "v"(v) : "memory");
}

// ---------------- zero fill ----------------
__global__ __launch_bounds__(256) void zero_kernel(float4* p, int n4) {
    int i = blockIdx.x * 256 + threadIdx.x;
    if (i < n4) p[i] = make_float4(0.f, 0.f, 0.f, 0.f);
}

// ---------------- P1: deformation + rotate + shift -> quantized records + bin counts ----------------
__global__ __launch_bounds__(256) void project_quant_kernel(
    const float* __restrict__ z_x, const float* __restrict__ z_y,
    const float* __restrict__ z_z, const float* __restrict__ Zb,
    const float* __restrict__ coords,
    const float* __restrict__ R, const float* __restrict__ shifts,
    unsigned* __restrict__ qrec, unsigned* __restrict__ counts)
{
    __shared__ float s_z[3][NIMG][NL];   // 24 KB
    __shared__ float s_R[NIMG][9];
    __shared__ float s_sh[NIMG][2];

    int tid = threadIdx.x;
    for (int i = tid; i < NIMG * NL; i += 256) {
        (&s_z[0][0][0])[i] = z_x[i];
        (&s_z[1][0][0])[i] = z_y[i];
        (&s_z[2][0][0])[i] = z_z[i];
    }
    for (int i = tid; i < NIMG * 9; i += 256) (&s_R[0][0])[i] = R[i];
    if (tid < NIMG * 2) (&s_sh[0][0])[tid] = shifts[tid];
    __syncthreads();

    int p = blockIdx.x * 256 + tid;
    bool valid = p < NPTS;
    int pc = valid ? p : (NPTS - 1);
    int lane = tid & 63;
    int sub = (p >> 12) & 3;             // wave-uniform (64 | 4096)

    float4 zr[16];
    const float4* Zr4 = (const float4*)(Zb + (size_t)pc * NL);
    #pragma unroll
    for (int i = 0; i < 16; ++i) zr[i] = Zr4[i];

    float cx0 = coords[3 * pc + 0];
    float cy0 = coords[3 * pc + 1];
    float cz0 = coords[3 * pc + 2];

    for (int b = 0; b < NIMG; ++b) {
        const float4* zx4 = (const float4*)s_z[0][b];
        const float4* zy4 = (const float4*)s_z[1][b];
        const float4* zz4 = (const float4*)s_z[2][b];
        float dx = 0.f, dy = 0.f, dz = 0.f;
        #pragma unroll
        for (int i = 0; i < 16; ++i) {
            float4 a = zx4[i];
            dx += a.x * zr[i].x + a.y * zr[i].y + a.z * zr[i].z + a.w * zr[i].w;
            float4 bb = zy4[i];
            dy += bb.x * zr[i].x + bb.y * zr[i].y + bb.z * zr[i].z + bb.w * zr[i].w;
            float4 c = zz4[i];
            dz += c.x * zr[i].x + c.y * zr[i].y + c.z * zr[i].z + c.w * zr[i].w;
        }
        float cx = cx0 + dx, cy = cy0 + dy, cz = cz0 + dz;
        const float* Rb = s_R[b];
        float px = Rb[0] * cx + Rb[1] * cy + Rb[2] * cz + s_sh[b][0] + 128.0f;
        float py = Rb[3] * cx + Rb[4] * cy + Rb[5] * cz + s_sh[b][1] + 128.0f;

        float x0f = floorf(px), y0f = floorf(py);
        float fx = px - x0f, fy = py - y0f;
        int xi0 = min(max((int)x0f, 0), 255);
        int yi0 = min(max((int)y0f, 0), 255);
        unsigned fxq = (unsigned)(fx * 256.f + 0.5f); if (fxq > 255u) fxq = 255u;
        unsigned fyq = (unsigned)(fy * 256.f + 0.5f); if (fyq > 255u) fyq = 255u;
        unsigned q = (unsigned)xi0 | ((unsigned)yi0 << 8) | (fxq << 16) | (fyq << 24);
        if (valid) qrec[(size_t)b * NPTS + p] = q;

        int band = valid ? (yi0 >> 5) : 8;
        for (int k = 0; k < 8; ++k) {
            unsigned long long m = __ballot(band == k);
            if (!m) continue;
            if (lane == __builtin_ctzll(m))
                atomicAdd(&counts[(b * 8 + k) * 4 + sub], (unsigned)__popcll(m));
        }
    }
}

// ---------------- P2: exclusive scan of 1024 bin counts -> offsets + cursors ----------------
__global__ __launch_bounds__(256) void scan_kernel(const unsigned* __restrict__ counts,
                                                   unsigned* __restrict__ offsets,
                                                   unsigned* __restrict__ cursors)
{
    __shared__ unsigned ps[256];
    int t = threadIdx.x;
    unsigned a0 = counts[4 * t], a1 = counts[4 * t + 1];
    unsigned a2 = counts[4 * t + 2], a3 = counts[4 * t + 3];
    unsigned s1 = a0 + a1, s2 = s1 + a2, tsum = s2 + a3;
    ps[t] = tsum; __syncthreads();
    unsigned acc = tsum;
    for (int off = 1; off < 256; off <<= 1) {
        unsigned v = (t >= off) ? ps[t - off] : 0u;
        __syncthreads();
        acc += v; ps[t] = acc;
        __syncthreads();
    }
    unsigned excl = acc - tsum;
    offsets[4 * t] = excl;           cursors[4 * t] = excl;
    offsets[4 * t + 1] = excl + a0;  cursors[4 * t + 1] = excl + a0;
    offsets[4 * t + 2] = excl + s1;  cursors[4 * t + 2] = excl + s1;
    offsets[4 * t + 3] = excl + s2;  cursors[4 * t + 3] = excl + s2;
}

// ---------------- P3: scatter records into band bins ----------------
__global__ __launch_bounds__(256) void scatter_kernel(
    const unsigned* __restrict__ qrec, const float* __restrict__ weights,
    unsigned* __restrict__ cursors, unsigned* __restrict__ binned_q,
    unsigned short* __restrict__ binned_wq)
{
    int b = blockIdx.y;
    int tid = threadIdx.x;
    int lane = tid & 63;
    int p0 = blockIdx.x * 4096;
    const unsigned* qb = qrec + (size_t)b * NPTS;

    for (int p = p0 + tid; p < p0 + 4096; p += 256) {
        bool valid = p < NPTS;
        unsigned q = valid ? qb[p] : 0u;
        int band = valid ? (int)((q >> 13) & 7u) : 8;
        int sub = (p >> 12) & 3;          // wave-uniform
        float w = valid ? weights[p] : 0.f;
        unsigned wq = (unsigned)(w * 65535.f + 0.5f); if (wq > 65535u) wq = 65535u;

        for (int k = 0; k < 8; ++k) {
            unsigned long long m = __ballot(band == k);
            if (!m) continue;
            int leader = (int)__builtin_ctzll(m);
            unsigned cnt = (unsigned)__popcll(m);
            unsigned base = 0;
            if (lane == leader) base = atomicAdd(&cursors[(b * 8 + k) * 4 + sub], cnt);
            base = (unsigned)__shfl((int)base, leader, 64);
            if (band == k) {
                unsigned rank = (unsigned)__popcll(m & ((1ULL << lane) - 1ULL));
                unsigned pos = base + rank;
                binned_q[pos] = q;
                binned_wq[pos] = (unsigned short)wq;
            }
        }
    }
}

// ---------------- P4: dense band splat from bins (ds_add_f32) ----------------
__global__ __launch_bounds__(256) void splat3_kernel(
    const unsigned* __restrict__ binned_q, const unsigned short* __restrict__ binned_wq,
    const unsigned* __restrict__ offsets, const unsigned* __restrict__ counts,
    float* __restrict__ img)
{
    __shared__ float tile[33 * NBOX];   // 33.8 KB (32 rows + 1 halo row)
    int idx = blockIdx.x;               // (b*NBAND+band)*QSUB + sub
    unsigned cnt = counts[idx];
    if (cnt == 0) return;
    int bb = idx >> 2;
    int b = bb >> 3, band = bb & 7;
    int y_lo = band * BROWS;
    unsigned off = offsets[idx];
    int tid = threadIdx.x;

    float4* t4 = (float4*)tile;
    for (int i = tid; i < 33 * NBOX / 4; i += 256) t4[i] = make_float4(0.f, 0.f, 0.f, 0.f);
    __syncthreads();

    for (unsigned i = off + tid; i < off + cnt; i += 256) {
        unsigned q = binned_q[i];
        float w = (float)binned_wq[i] * (1.0f / 65535.0f);
        int xi0 = q & 255u;
        int yi0 = (q >> 8) & 255u;
        float fx = (float)((q >> 16) & 255u) * (1.0f / 256.0f);
        float fy = (float)((q >> 24) & 255u) * (1.0f / 256.0f);
        int xi1 = min(xi0 + 1, 255);
        int r0 = yi0 - y_lo;
        int r1 = min(yi0 + 1, 255) - y_lo;
        float w00 = w * (1.f - fx) * (1.f - fy);
        float w10 = w * fx * (1.f - fy);
        float w01 = w * (1.f - fx) * fy;
        float w11 = w * fx * fy;
        lds_fadd(&tile[r0 * NBOX + xi0], w00);
        lds_fadd(&tile[r0 * NBOX + xi1], w10);
        lds_fadd(&tile[r1 * NBOX + xi0], w01);
        lds_fadd(&tile[r1 * NBOX + xi1], w11);
    }
    __syncthreads();

    int nrows = min(33, NBOX - y_lo);
    float* ib = img + (size_t)b * NBOX * NBOX + (size_t)y_lo * NBOX;
    for (int i = tid; i < nrows * NBOX; i += 256)
        unsafeAtomicAdd(ib + i, tile[i]);
}

// ---------------- fallback: fused splat with global atomics (small ws) ----------------
__global__ __launch_bounds__(256) void splat_kernel(
    const float* __restrict__ z_x, const float* __restrict__ z_y,
    const float* __restrict__ z_z, const float* __restrict__ Zb,
    const float* __restrict__ coords, const float* __restrict__ weights,
    const float* __restrict__ R, const float* __restrict__ shifts,
    float* __restrict__ img)
{
    __shared__ float s_z[3][NIMG][NL];
    __shared__ float s_R[NIMG][9];
    __shared__ float s_sh[NIMG][2];

    int tid = threadIdx.x;
    for (int i = tid; i < NIMG * NL; i += 256) {
        (&s_z[0][0][0])[i] = z_x[i];
        (&s_z[1][0][0])[i] = z_y[i];
        (&s_z[2][0][0])[i] = z_z[i];
    }
    for (int i = tid; i < NIMG * 9; i += 256) (&s_R[0][0])[i] = R[i];
    if (tid < NIMG * 2) (&s_sh[0][0])[tid] = shifts[tid];
    __syncthreads();

    int p = blockIdx.x * 256 + tid;
    if (p >= NPTS) return;

    float4 zr[16];
    const float4* Zr4 = (const float4*)(Zb + (size_t)p * NL);
    #pragma unroll
    for (int i = 0; i < 16; ++i) zr[i] = Zr4[i];

    float cx0 = coords[3 * p + 0];
    float cy0 = coords[3 * p + 1];
    float cz0 = coords[3 * p + 2];
    float w   = weights[p];

    for (int b = 0; b < NIMG; ++b) {
        const float4* zx4 = (const float4*)s_z[0][b];
        const float4* zy4 = (const float4*)s_z[1][b];
        const float4* zz4 = (const float4*)s_z[2][b];
        float dx = 0.f, dy = 0.f, dz = 0.f;
        #pragma unroll
        for (int i = 0; i < 16; ++i) {
            float4 a = zx4[i];
            dx += a.x * zr[i].x + a.y * zr[i].y + a.z * zr[i].z + a.w * zr[i].w;
            float4 bb = zy4[i];
            dy += bb.x * zr[i].x + bb.y * zr[i].y + bb.z * zr[i].z + bb.w * zr[i].w;
            float4 c = zz4[i];
            dz += c.x * zr[i].x + c.y * zr[i].y + c.z * zr[i].z + c.w * zr[i].w;
        }
        float cx = cx0 + dx, cy = cy0 + dy, cz = cz0 + dz;
        const float* Rb = s_R[b];
        float px = Rb[0] * cx + Rb[1] * cy + Rb[2] * cz + s_sh[b][0] + 128.0f;
        float py = Rb[3] * cx + Rb[4] * cy + Rb[5] * cz + s_sh[b][1] + 128.0f;

        float x0 = floorf(px), y0 = floorf(py);
        float fx = px - x0, fy = py - y0;
        int xi0 = min(max((int)x0, 0), NBOX - 1);
        int yi0 = min(max((int)y0, 0), NBOX - 1);
        int xi1 = min(xi0 + 1, NBOX - 1);
        int yi1 = min(yi0 + 1, NBOX - 1);

        float* ib = img + (size_t)b * NBOX * NBOX;
        unsafeAtomicAdd(ib + yi0 * NBOX + xi0, w * (1.f - fx) * (1.f - fy));
        unsafeAtomicAdd(ib + yi0 * NBOX + xi1, w * fx * (1.f - fy));
        unsafeAtomicAdd(ib + yi1 * NBOX + xi0, w * (1.f - fx) * fy);
        unsafeAtomicAdd(ib + yi1 * NBOX + xi1, w * fx * fy);
    }
}

// ---------------- 5x5 Gaussian blur ----------------
__global__ __launch_bounds__(256) void blur_kernel(const float* __restrict__ in,
                                                   float* __restrict__ out)
{
    int idx = blockIdx.x * 256 + threadIdx.x;
    int x = idx & (NBOX - 1);
    int y = (idx >> 8) & (NBOX - 1);
    int b = idx >> 16;
    const float* ib = in + (size_t)b * NBOX * NBOX;
    const float gw[5] = {0.0544886845f, 0.2442013420f, 0.4026199469f,
                         0.2442013420f, 0.0544886845f};
    float acc = 0.f;
    #pragma unroll
    for (int dy = -2; dy <= 2; ++dy) {
        int yy = y + dy;
        if (yy < 0 || yy > NBOX - 1) continue;
        float rs = 0.f;
        #pragma unroll
        for (int dx = -2; dx <= 2; ++dx) {
            int xx = x + dx;
            if (xx < 0 || xx > NBOX - 1) continue;
            rs += ib[yy * NBOX + xx] * gw[dx + 2];
        }
        acc += rs * gw[dy + 2];
    }
    out[idx] = acc;
}

// ---------------- 256-pt FFT with LDS twiddle table ----------------
__device__ __forceinline__ void fft_dif_t(float2* s, const float2* tw, int t) {
    #pragma unroll
    for (int st = 7; st >= 0; --st) {
        int half = 1 << st;
        int j  = t & (half - 1);
        int i1 = ((t >> st) << (st + 1)) + j;
        int i2 = i1 + half;
        float2 a = s[i1], b = s[i2];
        float2 w = tw[j << (7 - st)];
        float dxr = a.x - b.x, dxi = a.y - b.y;
        s[i1] = make_float2(a.x + b.x, a.y + b.y);
        s[i2] = make_float2(w.x * dxr - w.y * dxi, w.x * dxi + w.y * dxr);
        __syncthreads();
    }
}

__device__ __forceinline__ void fft_dit_t(float2* s, const float2* tw, int t) {
    #pragma unroll
    for (int st = 0; st < 8; ++st) {
        int half = 1 << st;
        int j  = t & (half - 1);
        int i1 = ((t >> st) << (st + 1)) + j;
        int i2 = i1 + half;
        float2 a = s[i1], b = s[i2];
        float2 w = tw[j << (7 - st)];
        float cs = w.x, sn = -w.y;
        float tr = cs * b.x - sn * b.y;
        float ti = cs * b.y + sn * b.x;
        s[i1] = make_float2(a.x + tr, a.y + ti);
        s[i2] = make_float2(a.x - tr, a.y - ti);
        __syncthreads();
    }
}

__device__ __forceinline__ void init_tw(float2* tw, int tid) {
    if (tid < 128) {
        float sn, cs;
        sincosf(-6.283185307179586f * (float)tid * (1.0f / 256.0f), &sn, &cs);
        tw[tid] = make_float2(cs, sn);
    }
}

__global__ __launch_bounds__(256) void fft_rows_fwd_kernel(const float* __restrict__ in,
                                                           float2* __restrict__ freq)
{
    __shared__ float2 s[2][NBOX];
    __shared__ float2 tw[128];
    int tid = threadIdx.x;
    int tx = tid & 127, ty = tid >> 7;
    init_tw(tw, tid);
    int row = blockIdx.x * 2 + ty;
    const float* rp = in + (size_t)row * NBOX;
    s[ty][tx]       = make_float2(rp[tx], 0.f);
    s[ty][tx + 128] = make_float2(rp[tx + 128], 0.f);
    __syncthreads();
    fft_dif_t(s[ty], tw, tx);
    float2* op = freq + (size_t)row * NBOX;
    op[tx]       = s[ty][tx];
    op[tx + 128] = s[ty][tx + 128];
}

__global__ __launch_bounds__(256) void fft_cols_ctf_kernel(float2* __restrict__ freq,
                                                           const float* __restrict__ ctf)
{
    __shared__ float2 s[2][NBOX];
    __shared__ float2 tw[128];
    int tid = threadIdx.x;
    int tx = tid & 127, ty = tid >> 7;
    init_tw(tw, tid);
    int gid = blockIdx.x * 2 + ty;
    int b = gid >> 8, x = gid & (NBOX - 1);
    float2* col = freq + (size_t)b * NBOX * NBOX + x;
    s[ty][tx]       = col[tx * NBOX];
    s[ty][tx + 128] = col[(tx + 128) * NBOX];
    __syncthreads();
    fft_dif_t(s[ty], tw, tx);
    const float* cb = ctf + (size_t)b * NBOX * NBOX + rev8(x);
    float c0 = cb[rev8(tx) * NBOX];
    float c1 = cb[rev8(tx + 128) * NBOX];
    s[ty][tx].x       *= c0;  s[ty][tx].y       *= c0;
    s[ty][tx + 128].x *= c1;  s[ty][tx + 128].y *= c1;
    __syncthreads();
    fft_dit_t(s[ty], tw, tx);
    const float inv = 1.0f / 256.0f;
    col[tx * NBOX]         = make_float2(s[ty][tx].x * inv,       s[ty][tx].y * inv);
    col[(tx + 128) * NBOX] = make_float2(s[ty][tx + 128].x * inv, s[ty][tx + 128].y * inv);
}

__global__ __launch_bounds__(256) void fft_rows_inv_kernel(const float2* __restrict__ freq,
                                                           float* __restrict__ out)
{
    __shared__ float2 s[2][NBOX];
    __shared__ float2 tw[128];
    int tid = threadIdx.x;
    int tx = tid & 127, ty = tid >> 7;
    init_tw(tw, tid);
    int row = blockIdx.x * 2 + ty;
    const float2* rp = freq + (size_t)row * NBOX;
    s[ty][tx]       = rp[tx];
    s[ty][tx + 128] = rp[tx + 128];
    __syncthreads();
    fft_dit_t(s[ty], tw, tx);
    const float inv = 1.0f / 256.0f;
    out[(size_t)row * NBOX + tx]       = s[ty][tx].x * inv;
    out[(size_t)row * NBOX + tx + 128] = s[ty][tx + 128].x * inv;
}

extern "C" void kernel_launch(void* const* d_in, const int* in_sizes, int n_in,
                              void* d_out, int out_size, void* d_ws, size_t ws_size,
                              hipStream_t stream)
{
    (void)in_sizes; (void)n_in; (void)out_size;
    const float* z_x     = (const float*)d_in[0];
    const float* z_y     = (const float*)d_in[1];
    const float* z_z     = (const float*)d_in[2];
    const float* Zb      = (const float*)d_in[3];
    const float* coords  = (const float*)d_in[4];
    const float* weights = (const float*)d_in[5];
    const float* R       = (const float*)d_in[6];
    const float* shifts  = (const float*)d_in[7];
    const float* ctf     = (const float*)d_in[8];
    float* out = (float*)d_out;

    const size_t NELEM = (size_t)NIMG * NBOX * NBOX;   // 2,097,152
    const size_t NPAIR = (size_t)NIMG * NPTS;          // 9.6 M
    char* base = (char*)d_ws;

    float*          img       = (float*)base;                                  // 8 MB
    unsigned*       qrec      = (unsigned*)(base + 8388608);                   // 38.4 MB
    unsigned*       binned_q  = (unsigned*)(base + 8388608 + 38400000);        // 38.4 MB
    unsigned short* binned_wq = (unsigned short*)(base + 8388608 + 76800000);  // 19.2 MB
    unsigned*       counts    = (unsigned*)(base + 8388608 + 96000000);        // 4 KB
    unsigned*       offsets   = counts + NBIN;
    unsigned*       cursors   = offsets + NBIN;
    // blur/freq alias dead bin regions during the image-space phase
    float*  blur = (float*)(base + 8388608);
    float2* freq = (float2*)(base + 16777216);
    const size_t required = 8388608 + 96000000 + 3 * NBIN * sizeof(unsigned);

    zero_kernel<<<(int)(NELEM / 4 + 255) / 256, 256, 0, stream>>>((float4*)img, (int)(NELEM / 4));

    if (ws_size >= required) {
        zero_kernel<<<1, 256, 0, stream>>>((float4*)counts, NBIN / 4);
        project_quant_kernel<<<(NPTS + 255) / 256, 256, 0, stream>>>(
            z_x, z_y, z_z, Zb, coords, R, shifts, qrec, counts);
        scan_kernel<<<1, 256, 0, stream>>>(counts, offsets, cursors);
        scatter_kernel<<<dim3((NPTS + 4095) / 4096, NIMG), 256, 0, stream>>>(
            qrec, weights, cursors, binned_q, binned_wq);
        splat3_kernel<<<NBIN, 256, 0, stream>>>(binned_q, binned_wq, offsets, counts, img);
    } else {
        splat_kernel<<<(NPTS + 255) / 256, 256, 0, stream>>>(z_x, z_y, z_z, Zb, coords,
                                                             weights, R, shifts, img);
    }

    blur_kernel<<<(int)(NELEM / 256), 256, 0, stream>>>(img, blur);
    fft_rows_fwd_kernel<<<NIMG * NBOX / 2, 256, 0, stream>>>(blur, freq);
    fft_cols_ctf_kernel<<<NIMG * NBOX / 2, 256, 0, stream>>>(freq, ctf);
    fft_rows_inv_kernel<<<NIMG * NBOX / 2, 256, 0, stream>>>(freq, out);
}

// Round 6
// 476.551 us; speedup vs baseline: 2.9763x; 2.9763x over previous
//
#include <hip/hip_runtime.h>
#include <hip/hip_bf16.h>

#define NIMG 32
#define NPTS 300000
#define NL   64
#define NBOX 256

#define BANDS  8
#define BROWS  32          // NBOX / BANDS
#define CHUNKS 2
#define CHPTS  (NPTS / CHUNKS)   // 150000
#define NGROUP (NIMG * CHUNKS)   // 64

__device__ __forceinline__ int rev8(int x) { return (int)(__brev((unsigned)x) >> 24); }

// native LDS float atomic add (ds_add_f32, no return).
// NO memory clobber: keeps the waitcnt pass from draining vmcnt/lgkmcnt before
// every atomic (that drain was the round-4/5 stall). volatile still pins
// program order vs. barriers/fences.
__device__ __forceinline__ void lds_fadd(float* p, float v) {
    unsigned off = (unsigned)(uintptr_t)p;
    asm volatile("ds_add_f32 %0, %1" :: "v"(off), "v"(v));
}

// ---------------- zero fill ----------------
__global__ __launch_bounds__(256) void zero_kernel(float4* p, int n4) {
    int i = blockIdx.x * 256 + threadIdx.x;
    if (i < n4) p[i] = make_float4(0.f, 0.f, 0.f, 0.f);
}

// ---------------- Pass 1: deformation + rotate + shift -> interleaved (px,py) ----------------
__global__ __launch_bounds__(256) void project_kernel(
    const float* __restrict__ z_x, const float* __restrict__ z_y,
    const float* __restrict__ z_z, const float* __restrict__ Zb,
    const float* __restrict__ coords,
    const float* __restrict__ R, const float* __restrict__ shifts,
    float2* __restrict__ pairs)
{
    __shared__ float s_z[3][NIMG][NL];   // 24 KB
    __shared__ float s_R[NIMG][9];
    __shared__ float s_sh[NIMG][2];

    int tid = threadIdx.x;
    for (int i = tid; i < NIMG * NL; i += 256) {
        (&s_z[0][0][0])[i] = z_x[i];
        (&s_z[1][0][0])[i] = z_y[i];
        (&s_z[2][0][0])[i] = z_z[i];
    }
    for (int i = tid; i < NIMG * 9; i += 256) (&s_R[0][0])[i] = R[i];
    if (tid < NIMG * 2) (&s_sh[0][0])[tid] = shifts[tid];
    __syncthreads();

    int p = blockIdx.x * 256 + tid;
    if (p >= NPTS) return;

    float4 zr[16];
    const float4* Zr4 = (const float4*)(Zb + (size_t)p * NL);
    #pragma unroll
    for (int i = 0; i < 16; ++i) zr[i] = Zr4[i];

    float cx0 = coords[3 * p + 0];
    float cy0 = coords[3 * p + 1];
    float cz0 = coords[3 * p + 2];

    for (int b = 0; b < NIMG; ++b) {
        const float4* zx4 = (const float4*)s_z[0][b];
        const float4* zy4 = (const float4*)s_z[1][b];
        const float4* zz4 = (const float4*)s_z[2][b];
        float dx = 0.f, dy = 0.f, dz = 0.f;
        #pragma unroll
        for (int i = 0; i < 16; ++i) {
            float4 a = zx4[i];
            dx += a.x * zr[i].x + a.y * zr[i].y + a.z * zr[i].z + a.w * zr[i].w;
            float4 bb = zy4[i];
            dy += bb.x * zr[i].x + bb.y * zr[i].y + bb.z * zr[i].z + bb.w * zr[i].w;
            float4 c = zz4[i];
            dz += c.x * zr[i].x + c.y * zr[i].y + c.z * zr[i].z + c.w * zr[i].w;
        }
        float cx = cx0 + dx, cy = cy0 + dy, cz = cz0 + dz;
        const float* Rb = s_R[b];
        float px = Rb[0] * cx + Rb[1] * cy + Rb[2] * cz + s_sh[b][0] + 128.0f;
        float py = Rb[3] * cx + Rb[4] * cy + Rb[5] * cz + s_sh[b][1] + 128.0f;
        pairs[(size_t)b * NPTS + p] = make_float2(px, py);
    }
}

// ---------------- Pass 2: LDS-privatized band splat (native ds_add_f32) ----------------
__global__ __launch_bounds__(256) void splat2_kernel(
    const float2* __restrict__ pairs, const float* __restrict__ weights,
    float* __restrict__ img)
{
    __shared__ float tile[BROWS * NBOX];   // 32 KB
    int tid = threadIdx.x;
    // id = group + NGROUP*band  -> all bands of a group land on the same XCD (64 % 8 == 0)
    int id = blockIdx.x;
    int band = id >> 6;           // 0..7
    int g    = id & 63;           // group = b*CHUNKS + c
    int b = g >> 1, c = g & 1;

    float4* t4 = (float4*)tile;
    for (int i = tid; i < BROWS * NBOX / 4; i += 256)
        t4[i] = make_float4(0.f, 0.f, 0.f, 0.f);
    __syncthreads();

    const int y_lo = band * BROWS;
    const float2* pp = pairs + (size_t)b * NPTS + (size_t)c * CHPTS;
    const float*  wp = weights + (size_t)c * CHPTS;

    for (int i = 4 * tid; i < CHPTS; i += 1024) {
        float4 q0 = *(const float4*)(pp + i);       // points i, i+1
        float4 q1 = *(const float4*)(pp + i + 2);   // points i+2, i+3
        float4 wv = *(const float4*)(wp + i);
        #pragma unroll
        for (int k = 0; k < 4; ++k) {
            float px = (k == 0) ? q0.x : (k == 1) ? q0.z : (k == 2) ? q1.x : q1.z;
            float py = (k == 0) ? q0.y : (k == 1) ? q0.w : (k == 2) ? q1.y : q1.w;
            float w  = (k == 0) ? wv.x : (k == 1) ? wv.y : (k == 2) ? wv.z : wv.w;
            float x0 = floorf(px), y0 = floorf(py);
            float fx = px - x0, fy = py - y0;
            int xi0 = min(max((int)x0, 0), NBOX - 1);
            int yi0 = min(max((int)y0, 0), NBOX - 1);
            int xi1 = min(xi0 + 1, NBOX - 1);
            int yi1 = min(yi0 + 1, NBOX - 1);
            float w00 = w * (1.f - fx) * (1.f - fy);
            float w10 = w * fx * (1.f - fy);
            float w01 = w * (1.f - fx) * fy;
            float w11 = w * fx * fy;
            int r0 = yi0 - y_lo, r1 = yi1 - y_lo;
            if ((unsigned)r0 < BROWS) {
                lds_fadd(&tile[r0 * NBOX + xi0], w00);
                lds_fadd(&tile[r0 * NBOX + xi1], w10);
            }
            if ((unsigned)r1 < BROWS) {
                lds_fadd(&tile[r1 * NBOX + xi0], w01);
                lds_fadd(&tile[r1 * NBOX + xi1], w11);
            }
        }
    }
    // drain the asm DS atomics (invisible to the compiler's waitcnt pass)
    asm volatile("s_waitcnt lgkmcnt(0)" ::: "memory");
    __syncthreads();
    float* ib = img + (size_t)b * NBOX * NBOX + (size_t)y_lo * NBOX;
    for (int i = tid; i < BROWS * NBOX; i += 256)
        unsafeAtomicAdd(ib + i, tile[i]);
}

// ---------------- fallback: original fused splat (global atomics) ----------------
__global__ __launch_bounds__(256) void splat_kernel(
    const float* __restrict__ z_x, const float* __restrict__ z_y,
    const float* __restrict__ z_z, const float* __restrict__ Zb,
    const float* __restrict__ coords, const float* __restrict__ weights,
    const float* __restrict__ R, const float* __restrict__ shifts,
    float* __restrict__ img)
{
    __shared__ float s_z[3][NIMG][NL];
    __shared__ float s_R[NIMG][9];
    __shared__ float s_sh[NIMG][2];

    int tid = threadIdx.x;
    for (int i = tid; i < NIMG * NL; i += 256) {
        (&s_z[0][0][0])[i] = z_x[i];
        (&s_z[1][0][0])[i] = z_y[i];
        (&s_z[2][0][0])[i] = z_z[i];
    }
    for (int i = tid; i < NIMG * 9; i += 256) (&s_R[0][0])[i] = R[i];
    if (tid < NIMG * 2) (&s_sh[0][0])[tid] = shifts[tid];
    __syncthreads();

    int p = blockIdx.x * 256 + tid;
    if (p >= NPTS) return;

    float4 zr[16];
    const float4* Zr4 = (const float4*)(Zb + (size_t)p * NL);
    #pragma unroll
    for (int i = 0; i < 16; ++i) zr[i] = Zr4[i];

    float cx0 = coords[3 * p + 0];
    float cy0 = coords[3 * p + 1];
    float cz0 = coords[3 * p + 2];
    float w   = weights[p];

    for (int b = 0; b < NIMG; ++b) {
        const float4* zx4 = (const float4*)s_z[0][b];
        const float4* zy4 = (const float4*)s_z[1][b];
        const float4* zz4 = (const float4*)s_z[2][b];
        float dx = 0.f, dy = 0.f, dz = 0.f;
        #pragma unroll
        for (int i = 0; i < 16; ++i) {
            float4 a = zx4[i];
            dx += a.x * zr[i].x + a.y * zr[i].y + a.z * zr[i].z + a.w * zr[i].w;
            float4 bb = zy4[i];
            dy += bb.x * zr[i].x + bb.y * zr[i].y + bb.z * zr[i].z + bb.w * zr[i].w;
            float4 c = zz4[i];
            dz += c.x * zr[i].x + c.y * zr[i].y + c.z * zr[i].z + c.w * zr[i].w;
        }
        float cx = cx0 + dx, cy = cy0 + dy, cz = cz0 + dz;
        const float* Rb = s_R[b];
        float px = Rb[0] * cx + Rb[1] * cy + Rb[2] * cz + s_sh[b][0] + 128.0f;
        float py = Rb[3] * cx + Rb[4] * cy + Rb[5] * cz + s_sh[b][1] + 128.0f;

        float x0 = floorf(px), y0 = floorf(py);
        float fx = px - x0, fy = py - y0;
        int xi0 = min(max((int)x0, 0), NBOX - 1);
        int yi0 = min(max((int)y0, 0), NBOX - 1);
        int xi1 = min(xi0 + 1, NBOX - 1);
        int yi1 = min(yi0 + 1, NBOX - 1);

        float* ib = img + (size_t)b * NBOX * NBOX;
        unsafeAtomicAdd(ib + yi0 * NBOX + xi0, w * (1.f - fx) * (1.f - fy));
        unsafeAtomicAdd(ib + yi0 * NBOX + xi1, w * fx * (1.f - fy));
        unsafeAtomicAdd(ib + yi1 * NBOX + xi0, w * (1.f - fx) * fy);
        unsafeAtomicAdd(ib + yi1 * NBOX + xi1, w * fx * fy);
    }
}

// ---------------- 5x5 Gaussian blur (zero-padded SAME) ----------------
__global__ __launch_bounds__(256) void blur_kernel(const float* __restrict__ in,
                                                   float* __restrict__ out)
{
    int idx = blockIdx.x * 256 + threadIdx.x;
    int x = idx & (NBOX - 1);
    int y = (idx >> 8) & (NBOX - 1);
    int b = idx >> 16;
    const float* ib = in + (size_t)b * NBOX * NBOX;
    const float gw[5] = {0.0544886845f, 0.2442013420f, 0.4026199469f,
                         0.2442013420f, 0.0544886845f};
    float acc = 0.f;
    #pragma unroll
    for (int dy = -2; dy <= 2; ++dy) {
        int yy = y + dy;
        if (yy < 0 || yy > NBOX - 1) continue;
        float rs = 0.f;
        #pragma unroll
        for (int dx = -2; dx <= 2; ++dx) {
            int xx = x + dx;
            if (xx < 0 || xx > NBOX - 1) continue;
            rs += ib[yy * NBOX + xx] * gw[dx + 2];
        }
        acc += rs * gw[dy + 2];
    }
    out[idx] = acc;
}

// ---------------- 256-pt FFT with LDS twiddle table ----------------
__device__ __forceinline__ void fft_dif_t(float2* s, const float2* tw, int t) {
    #pragma unroll
    for (int st = 7; st >= 0; --st) {
        int half = 1 << st;
        int j  = t & (half - 1);
        int i1 = ((t >> st) << (st + 1)) + j;
        int i2 = i1 + half;
        float2 a = s[i1], b = s[i2];
        float2 w = tw[j << (7 - st)];
        float dxr = a.x - b.x, dxi = a.y - b.y;
        s[i1] = make_float2(a.x + b.x, a.y + b.y);
        s[i2] = make_float2(w.x * dxr - w.y * dxi, w.x * dxi + w.y * dxr);
        __syncthreads();
    }
}

__device__ __forceinline__ void fft_dit_t(float2* s, const float2* tw, int t) {
    #pragma unroll
    for (int st = 0; st < 8; ++st) {
        int half = 1 << st;
        int j  = t & (half - 1);
        int i1 = ((t >> st) << (st + 1)) + j;
        int i2 = i1 + half;
        float2 a = s[i1], b = s[i2];
        float2 w = tw[j << (7 - st)];
        float cs = w.x, sn = -w.y;
        float tr = cs * b.x - sn * b.y;
        float ti = cs * b.y + sn * b.x;
        s[i1] = make_float2(a.x + tr, a.y + ti);
        s[i2] = make_float2(a.x - tr, a.y - ti);
        __syncthreads();
    }
}

__device__ __forceinline__ void init_tw(float2* tw, int tid) {
    if (tid < 128) {
        float sn, cs;
        sincosf(-6.283185307179586f * (float)tid * (1.0f / 256.0f), &sn, &cs);
        tw[tid] = make_float2(cs, sn);
    }
}

__global__ __launch_bounds__(256) void fft_rows_fwd_kernel(const float* __restrict__ in,
                                                           float2* __restrict__ freq)
{
    __shared__ float2 s[2][NBOX];
    __shared__ float2 tw[128];
    int tid = threadIdx.x;
    int tx = tid & 127, ty = tid >> 7;
    init_tw(tw, tid);
    int row = blockIdx.x * 2 + ty;
    const float* rp = in + (size_t)row * NBOX;
    s[ty][tx]       = make_float2(rp[tx], 0.f);
    s[ty][tx + 128] = make_float2(rp[tx + 128], 0.f);
    __syncthreads();
    fft_dif_t(s[ty], tw, tx);
    float2* op = freq + (size_t)row * NBOX;
    op[tx]       = s[ty][tx];
    op[tx + 128] = s[ty][tx + 128];
}

__global__ __launch_bounds__(256) void fft_cols_ctf_kernel(float2* __restrict__ freq,
                                                           const float* __restrict__ ctf)
{
    __shared__ float2 s[2][NBOX];
    __shared__ float2 tw[128];
    int tid = threadIdx.x;
    int tx = tid & 127, ty = tid >> 7;
    init_tw(tw, tid);
    int gid = blockIdx.x * 2 + ty;
    int b = gid >> 8, x = gid & (NBOX - 1);
    float2* col = freq + (size_t)b * NBOX * NBOX + x;
    s[ty][tx]       = col[tx * NBOX];
    s[ty][tx + 128] = col[(tx + 128) * NBOX];
    __syncthreads();
    fft_dif_t(s[ty], tw, tx);
    const float* cb = ctf + (size_t)b * NBOX * NBOX + rev8(x);
    float c0 = cb[rev8(tx) * NBOX];
    float c1 = cb[rev8(tx + 128) * NBOX];
    s[ty][tx].x       *= c0;  s[ty][tx].y       *= c0;
    s[ty][tx + 128].x *= c1;  s[ty][tx + 128].y *= c1;
    __syncthreads();
    fft_dit_t(s[ty], tw, tx);
    const float inv = 1.0f / 256.0f;
    col[tx * NBOX]         = make_float2(s[ty][tx].x * inv,       s[ty][tx].y * inv);
    col[(tx + 128) * NBOX] = make_float2(s[ty][tx + 128].x * inv, s[ty][tx + 128].y * inv);
}

__global__ __launch_bounds__(256) void fft_rows_inv_kernel(const float2* __restrict__ freq,
                                                           float* __restrict__ out)
{
    __shared__ float2 s[2][NBOX];
    __shared__ float2 tw[128];
    int tid = threadIdx.x;
    int tx = tid & 127, ty = tid >> 7;
    init_tw(tw, tid);
    int row = blockIdx.x * 2 + ty;
    const float2* rp = freq + (size_t)row * NBOX;
    s[ty][tx]       = rp[tx];
    s[ty][tx + 128] = rp[tx + 128];
    __syncthreads();
    fft_dit_t(s[ty], tw, tx);
    const float inv = 1.0f / 256.0f;
    out[(size_t)row * NBOX + tx]       = s[ty][tx].x * inv;
    out[(size_t)row * NBOX + tx + 128] = s[ty][tx + 128].x * inv;
}

extern "C" void kernel_launch(void* const* d_in, const int* in_sizes, int n_in,
                              void* d_out, int out_size, void* d_ws, size_t ws_size,
                              hipStream_t stream)
{
    (void)in_sizes; (void)n_in; (void)out_size;
    const float* z_x     = (const float*)d_in[0];
    const float* z_y     = (const float*)d_in[1];
    const float* z_z     = (const float*)d_in[2];
    const float* Zb      = (const float*)d_in[3];
    const float* coords  = (const float*)d_in[4];
    const float* weights = (const float*)d_in[5];
    const float* R       = (const float*)d_in[6];
    const float* shifts  = (const float*)d_in[7];
    const float* ctf     = (const float*)d_in[8];
    float* out = (float*)d_out;

    const size_t NELEM = (size_t)NIMG * NBOX * NBOX;           // 2,097,152
    const size_t NPAIR = (size_t)NIMG * NPTS;                  // 9.6 M
    float*  img  = (float*)d_ws;
    float*  blur = img + NELEM;
    float2* freq = (float2*)(blur + NELEM);
    float2* pairs = (float2*)(freq + NELEM);
    const size_t required = (4 * NELEM + 2 * NPAIR) * sizeof(float);

    zero_kernel<<<(int)(NELEM / 4 + 255) / 256, 256, 0, stream>>>((float4*)img, (int)(NELEM / 4));

    if (ws_size >= required) {
        project_kernel<<<(NPTS + 255) / 256, 256, 0, stream>>>(z_x, z_y, z_z, Zb, coords,
                                                               R, shifts, pairs);
        splat2_kernel<<<NGROUP * BANDS, 256, 0, stream>>>(pairs, weights, img);
    } else {
        splat_kernel<<<(NPTS + 255) / 256, 256, 0, stream>>>(z_x, z_y, z_z, Zb, coords,
                                                             weights, R, shifts, img);
    }

    blur_kernel<<<(int)(NELEM / 256), 256, 0, stream>>>(img, blur);
    fft_rows_fwd_kernel<<<NIMG * NBOX / 2, 256, 0, stream>>>(blur, freq);
    fft_cols_ctf_kernel<<<NIMG * NBOX / 2, 256, 0, stream>>>(freq, ctf);
    fft_rows_inv_kernel<<<NIMG * NBOX / 2, 256, 0, stream>>>(freq, out);
}